// Round 8
// baseline (165.375 us; speedup 1.0000x reference)
//
#include <hip/hip_runtime.h>

typedef short bf16x8 __attribute__((ext_vector_type(8)));
typedef float f32x4  __attribute__((ext_vector_type(4)));
typedef short sh4    __attribute__((ext_vector_type(4)));
typedef float fl4    __attribute__((ext_vector_type(4)));
typedef unsigned u32x2 __attribute__((ext_vector_type(2)));
typedef unsigned u32x4 __attribute__((ext_vector_type(4)));

#define B_N  4
#define C_N  256
#define NH_N 8
#define DK_N 32
#define N_N  1024
#define KN_N 3072

#if defined(__has_builtin)
#if __has_builtin(__builtin_amdgcn_permlane32_swap) && __has_builtin(__builtin_amdgcn_permlane16_swap)
#define USE_PERMLANE 1
#endif
#endif
#ifndef USE_PERMLANE
#define USE_PERMLANE 0
#endif

__device__ __forceinline__ short f2bf(float f) {   // RNE
    union { float f; unsigned u; } v; v.f = f;
    unsigned r = v.u + 0x7fffu + ((v.u >> 16) & 1u);
    return (short)(r >> 16);
}
__device__ __forceinline__ unsigned fbits(float f) {
    union { float f; unsigned u; } v; v.f = f; return v.u;
}

// Full-rate-VALU exp2: evicts the work from the (per-CU shared, saturated)
// transcendental pipe. |s| <= ~12, bf16-accuracy target; Taylor deg-3 on
// f in [-0.5,0.5] has rel err <= 6.5e-4.
__device__ __forceinline__ float fexp2(float s) {
    float n = __builtin_rintf(s);                       // v_rndne_f32
    float f = s - n;
    float t = __builtin_fmaf(f, 0.0555041086f, 0.2402265069f);
    t = __builtin_fmaf(f, t, 0.6931471806f);
    t = __builtin_fmaf(f, t, 1.0f);
    return ldexpf(t, (int)n);                           // v_cvt_i32 + v_ldexp
}

// ------------- kernel 1: prep streams + (z==12) weight fp32->bf16 -----------
__global__ __launch_bounds__(256) void prep_kernel(
    const float* __restrict__ x0, const float* __restrict__ x1,
    const float* __restrict__ x2, const float* __restrict__ g0,
    const float* __restrict__ g1, const float* __restrict__ g2,
    const float* __restrict__ Wq, const float* __restrict__ Wk,
    const float* __restrict__ Wv, const float* __restrict__ Wo,
    short* __restrict__ Xt, short* __restrict__ Wbf) {
    if (blockIdx.z == 12) {
        int t = (blockIdx.y * 16 + blockIdx.x) * 256 + threadIdx.x;  // 0..16383
#pragma unroll
        for (int m = 0; m < 4; ++m) {
            const float* src = (m == 0) ? Wq : (m == 1) ? Wk : (m == 2) ? Wv : Wo;
            fl4 v = *reinterpret_cast<const fl4*>(src + t * 4);
            sh4 o;
            o.x = f2bf(v.x); o.y = f2bf(v.y); o.z = f2bf(v.z); o.w = f2bf(v.w);
            *reinterpret_cast<sh4*>(Wbf + m * 65536 + t * 4) = o;
        }
        return;
    }
    __shared__ float tile[64][65];
    int bs = blockIdx.z; int b = bs / 3; int s = bs - b * 3;
    int c0 = blockIdx.y * 64, n0 = blockIdx.x * 64;
    const float* xs = (s == 0) ? x0 : (s == 1) ? x1 : x2;
    float g = (s == 0) ? g0[0] : (s == 1) ? g1[0] : g2[0];
    int tx = threadIdx.x & 63, ty = threadIdx.x >> 6;
    const float* src = xs + (b * C_N + c0) * N_N + n0;
#pragma unroll
    for (int r = 0; r < 16; ++r) {
        int cl = ty * 16 + r;
        tile[cl][tx] = src[cl * N_N + tx] * g;
    }
    __syncthreads();
    short* dst = Xt + ((size_t)bs * N_N + n0) * C_N + c0;
#pragma unroll
    for (int r = 0; r < 16; ++r) {
        int nl = ty * 16 + r;
        dst[nl * C_N + tx] = f2bf(tile[tx][nl]);
    }
}

// ---------------- kernel 2: QKV GEMM  grid(112 ct, 4 mt, 4 b) ---------------
__global__ __launch_bounds__(256) void qkv_kernel(
    const short* __restrict__ Wbf, const float* __restrict__ bq,
    const float* __restrict__ bk, const float* __restrict__ bv,
    const short* __restrict__ Xt, short* __restrict__ Qs,
    short* __restrict__ Ks, short* __restrict__ Vt) {
    __shared__ short SM[5120];   // Q/K: [2][64][40]; V: [64][72]
    int b = blockIdx.z, mt = blockIdx.y, ct = blockIdx.x;
    int lane = threadIdx.x & 63, w = threadIdx.x >> 6;
    int l16 = lane & 15, quad = lane >> 4;
    int m0 = mt * 64;

    int type, s, n0;
    if (ct < 16)      { type = 0; s = 0;                 n0 = ct * 64; }
    else if (ct < 64) { type = 1; int c2 = ct - 16; s = c2 >> 4; n0 = (c2 & 15) * 64; }
    else              { type = 2; int c2 = ct - 64; s = c2 >> 4; n0 = (c2 & 15) * 64; }

    f32x4 acc[4];
#pragma unroll
    for (int i = 0; i < 4; ++i) acc[i] = f32x4{0.f, 0.f, 0.f, 0.f};

    if (type < 2) {
        const short* A    = Wbf + type * 65536;
        const float* bias = (type == 0) ? bq : bk;
        const short* Bsrc = Xt + ((size_t)(b * 3 + s) * N_N + n0) * C_N;
        int arow = m0 + w * 16 + l16;
#pragma unroll
        for (int kc = 0; kc < 256; kc += 32) {
            bf16x8 a = *reinterpret_cast<const bf16x8*>(A + arow * C_N + kc + quad * 8);
#pragma unroll
            for (int nt = 0; nt < 4; ++nt) {
                bf16x8 bb = *reinterpret_cast<const bf16x8*>(Bsrc + (nt * 16 + l16) * C_N + kc + quad * 8);
                acc[nt] = __builtin_amdgcn_mfma_f32_16x16x32_bf16(a, bb, acc[nt], 0, 0, 0);
            }
        }
        const float QSCALE = 0.17677669529663687f * 1.4426950408889634f;
        int row0 = m0 + w * 16 + quad * 4;
        float b0_ = bias[row0], b1_ = bias[row0 + 1], b2_ = bias[row0 + 2], b3_ = bias[row0 + 3];
        int dk0 = (w & 1) * 16 + quad * 4;
        short* Tp = SM + (w >> 1) * 2560 + dk0;    // + pos*40
#pragma unroll
        for (int nt = 0; nt < 4; ++nt) {
            int pos = nt * 16 + l16;
            float v0 = acc[nt][0] + b0_, v1 = acc[nt][1] + b1_;
            float v2 = acc[nt][2] + b2_, v3 = acc[nt][3] + b3_;
            sh4 pk;
            if (type == 0) {
                pk.x = f2bf(v0 * QSCALE); pk.y = f2bf(v1 * QSCALE);
                pk.z = f2bf(v2 * QSCALE); pk.w = f2bf(v3 * QSCALE);
            } else {
                pk.x = f2bf(v0); pk.y = f2bf(v1); pk.z = f2bf(v2); pk.w = f2bf(v3);
            }
            *reinterpret_cast<sh4*>(Tp + pos * 40) = pk;
        }
        __syncthreads();
        int t = threadIdx.x;
        int pos_l = t >> 2, seg = t & 3;
#pragma unroll
        for (int hl = 0; hl < 2; ++hl) {
            bf16x8 vv = *reinterpret_cast<const bf16x8*>(SM + hl * 2560 + pos_l * 40 + seg * 8);
            int h = 2 * mt + hl;
            if (type == 0) {
                size_t base = ((size_t)(b * NH_N + h) * N_N + n0) * DK_N;
                *reinterpret_cast<bf16x8*>(Qs + base + t * 8) = vv;
            } else {
                size_t base = ((size_t)(b * NH_N + h) * KN_N + s * N_N + n0) * DK_N;
                *reinterpret_cast<bf16x8*>(Ks + base + t * 8) = vv;
            }
        }
    } else {
        const short* Bw   = Wbf + 2 * 65536;
        const short* Asrc = Xt + (size_t)(b * 3 + s) * N_N * C_N;
        int apos = n0 + w * 16 + l16;
#pragma unroll
        for (int kc = 0; kc < 256; kc += 32) {
            bf16x8 ax = *reinterpret_cast<const bf16x8*>(Asrc + (size_t)apos * C_N + kc + quad * 8);
#pragma unroll
            for (int c2 = 0; c2 < 4; ++c2) {
                bf16x8 bw = *reinterpret_cast<const bf16x8*>(Bw + (size_t)(m0 + c2 * 16 + l16) * C_N + kc + quad * 8);
                acc[c2] = __builtin_amdgcn_mfma_f32_16x16x32_bf16(ax, bw, acc[c2], 0, 0, 0);
            }
        }
        int key0 = w * 16 + quad * 4;
#pragma unroll
        for (int c2 = 0; c2 < 4; ++c2) {
            int row = c2 * 16 + l16;
            float bb_ = bv[m0 + row];
            sh4 pk;
            pk.x = f2bf(acc[c2][0] + bb_); pk.y = f2bf(acc[c2][1] + bb_);
            pk.z = f2bf(acc[c2][2] + bb_); pk.w = f2bf(acc[c2][3] + bb_);
            *reinterpret_cast<sh4*>(SM + row * 72 + key0) = pk;
        }
        __syncthreads();
        int t = threadIdx.x;
#pragma unroll
        for (int i = 0; i < 2; ++i) {
            int ch = t + i * 256;
            int row = ch >> 3, seg = ch & 7;
            bf16x8 vv = *reinterpret_cast<const bf16x8*>(SM + row * 72 + seg * 8);
            int co = m0 + row;
            int h = co >> 5, d = co & 31;
            *reinterpret_cast<bf16x8*>(
                Vt + ((size_t)(b * NH_N + h) * DK_N + d) * KN_N + s * N_N + n0 + seg * 8) = vv;
        }
    }
}

// -------- kernel 3: fused attention, 4 waves = 4 key-splits -----------------
// Ones-row trick: softmax denominator computed by the PV MFMA.
// fexp2: softmax numerator on the full-rate VALU (trans pipe freed).
struct Frags { bf16x8 k0, k1, k2, k3, v00, v01, v10, v11; };

__device__ __forceinline__ Frags ldfr(const short* Kp, const short* Vp0, int k0) {
    Frags f;
    f.k0  = *reinterpret_cast<const bf16x8*>(Kp + (k0 +  0) * DK_N);
    f.k1  = *reinterpret_cast<const bf16x8*>(Kp + (k0 + 16) * DK_N);
    f.k2  = *reinterpret_cast<const bf16x8*>(Kp + (k0 + 32) * DK_N);
    f.k3  = *reinterpret_cast<const bf16x8*>(Kp + (k0 + 48) * DK_N);
    f.v00 = *reinterpret_cast<const bf16x8*>(Vp0 + k0);
    f.v01 = *reinterpret_cast<const bf16x8*>(Vp0 + 16 * KN_N + k0);
    f.v10 = *reinterpret_cast<const bf16x8*>(Vp0 + k0 + 32);
    f.v11 = *reinterpret_cast<const bf16x8*>(Vp0 + 16 * KN_N + k0 + 32);
    return f;
}

#define EXPPACK(sv, Ra, Rb) {                                   \
    float p0 = fexp2(sv[0]);                                    \
    float p1 = fexp2(sv[1]);                                    \
    float p2 = fexp2(sv[2]);                                    \
    float p3 = fexp2(sv[3]);                                    \
    Ra = __builtin_amdgcn_perm(fbits(p1), fbits(p0), 0x07060302u); \
    Rb = __builtin_amdgcn_perm(fbits(p3), fbits(p2), 0x07060302u); \
}

#if USE_PERMLANE
// In-register C-layout -> B-layout transpose via gfx950 permlane swaps.
#define PVSTEP(RA0, RA1, RB0, RB1, VF0, VF1, O0, O1, O2) {             \
    unsigned x0 = RA0, y0 = RB0, x1 = RA1, y1 = RB1;                   \
    u32x2 r_;                                                          \
    r_ = __builtin_amdgcn_permlane32_swap(x0, y0, false, false); x0 = r_.x; y0 = r_.y; \
    r_ = __builtin_amdgcn_permlane16_swap(x0, y0, false, false); x0 = r_.x; y0 = r_.y; \
    r_ = __builtin_amdgcn_permlane32_swap(x1, y1, false, false); x1 = r_.x; y1 = r_.y; \
    r_ = __builtin_amdgcn_permlane16_swap(x1, y1, false, false); x1 = r_.x; y1 = r_.y; \
    union { u32x4 u; bf16x8 b; } pf_; pf_.u = u32x4{x0, x1, y0, y1};   \
    O0 = __builtin_amdgcn_mfma_f32_16x16x32_bf16(VF0, pf_.b, O0, 0, 0, 0); \
    O1 = __builtin_amdgcn_mfma_f32_16x16x32_bf16(VF1, pf_.b, O1, 0, 0, 0); \
    O2 = __builtin_amdgcn_mfma_f32_16x16x32_bf16(ones8, pf_.b, O2, 0, 0, 0); \
}
#else
// Fallback (also satisfies the host compile pass): per-wave-private LDS
// round-trip, no barrier needed.
#define PVSTEP(RA0, RA1, RB0, RB1, VF0, VF1, O0, O1, O2) {             \
    union { u32x2 u; sh4 s; } wa_, wb_;                                \
    wa_.u = u32x2{RA0, RA1}; wb_.u = u32x2{RB0, RB1};                  \
    *reinterpret_cast<sh4*>(&PT[w][l16][quad * 4])      = wa_.s;       \
    *reinterpret_cast<sh4*>(&PT[w][l16][16 + quad * 4]) = wb_.s;       \
    bf16x8 pf_ = *reinterpret_cast<bf16x8*>(&PT[w][l16][quad * 8]);    \
    O0 = __builtin_amdgcn_mfma_f32_16x16x32_bf16(VF0, pf_, O0, 0, 0, 0); \
    O1 = __builtin_amdgcn_mfma_f32_16x16x32_bf16(VF1, pf_, O1, 0, 0, 0); \
    O2 = __builtin_amdgcn_mfma_f32_16x16x32_bf16(ones8, pf_, O2, 0, 0, 0); \
}
#endif

// One 64-key tile x one 16-row q-fragment
#define PROCJ(f, QF, O0, O1, O2) {                                       \
    f32x4 s0 = __builtin_amdgcn_mfma_f32_16x16x32_bf16(f.k0, QF, zero, 0, 0, 0); \
    f32x4 s1 = __builtin_amdgcn_mfma_f32_16x16x32_bf16(f.k1, QF, zero, 0, 0, 0); \
    f32x4 s2 = __builtin_amdgcn_mfma_f32_16x16x32_bf16(f.k2, QF, zero, 0, 0, 0); \
    f32x4 s3 = __builtin_amdgcn_mfma_f32_16x16x32_bf16(f.k3, QF, zero, 0, 0, 0); \
    unsigned R00, R01, R10, R11, R20, R21, R30, R31;                     \
    EXPPACK(s0, R00, R01); EXPPACK(s1, R10, R11);                        \
    EXPPACK(s2, R20, R21); EXPPACK(s3, R30, R31);                        \
    PVSTEP(R00, R01, R10, R11, f.v00, f.v01, O0, O1, O2);                \
    PVSTEP(R20, R21, R30, R31, f.v10, f.v11, O0, O1, O2);                \
}

#define PROCALL(f) {                                                     \
    PROCJ(f, qf0, o00, o01, l0);                                         \
    PROCJ(f, qf1, o10, o11, l1);                                         \
    PROCJ(f, qf2, o20, o21, l2);                                         \
    PROCJ(f, qf3, o30, o31, l3);                                         \
}

__global__ __launch_bounds__(256, 2) void attn_kernel(
    const short* __restrict__ Qs, const short* __restrict__ Ks,
    const short* __restrict__ Vt, short* __restrict__ Ot) {
    __shared__ float OL[4][64][36];   // [split][q][d] partial O, 36 KB
    __shared__ float Ll[4][64];       // [split][q] partial rowsum
#if !USE_PERMLANE
    __shared__ short PT[4][16][36];
#endif

    int bh = blockIdx.x;
    int q0 = blockIdx.y * 64;
    int t = threadIdx.x, lane = t & 63, w = t >> 6;   // w = key-split 0..3
    int l16 = lane & 15, quad = lane >> 4;

    // all-ones A-fragment row 0 (m==0 lanes hold bf16 1.0 x8)
    union { u32x4 u; bf16x8 b; } ones_;
    unsigned ov = (l16 == 0) ? 0x3F803F80u : 0u;
    ones_.u = u32x4{ov, ov, ov, ov};
    const bf16x8 ones8 = ones_.b;

    const short* Qbase = Qs + ((size_t)bh * N_N + q0 + l16) * DK_N + quad * 8;
    bf16x8 qf0 = *reinterpret_cast<const bf16x8*>(Qbase + 0 * 16 * DK_N);
    bf16x8 qf1 = *reinterpret_cast<const bf16x8*>(Qbase + 1 * 16 * DK_N);
    bf16x8 qf2 = *reinterpret_cast<const bf16x8*>(Qbase + 2 * 16 * DK_N);
    bf16x8 qf3 = *reinterpret_cast<const bf16x8*>(Qbase + 3 * 16 * DK_N);
    const short* Kp  = Ks + ((size_t)bh * KN_N + l16) * DK_N + quad * 8;
    const short* Vp0 = Vt + ((size_t)bh * DK_N + l16) * KN_N + quad * 8;

    const f32x4 zero = {0.f, 0.f, 0.f, 0.f};
    f32x4 o00 = zero, o01 = zero, o10 = zero, o11 = zero;
    f32x4 o20 = zero, o21 = zero, o30 = zero, o31 = zero;
    f32x4 l0 = zero, l1 = zero, l2 = zero, l3 = zero;
    int kbase = w * 768;              // this wave's 768-key slice, 12 tiles

    Frags cur = ldfr(Kp, Vp0, kbase);
#pragma unroll 2
    for (int i = 0; i < 11; ++i) {
        Frags nxt = ldfr(Kp, Vp0, kbase + (i + 1) * 64);   // prefetch next tile
        PROCALL(cur);
        cur = nxt;
    }
    PROCALL(cur);

    *reinterpret_cast<fl4*>(&OL[w][ 0 + l16][quad * 4])      = o00;
    *reinterpret_cast<fl4*>(&OL[w][ 0 + l16][16 + quad * 4]) = o01;
    *reinterpret_cast<fl4*>(&OL[w][16 + l16][quad * 4])      = o10;
    *reinterpret_cast<fl4*>(&OL[w][16 + l16][16 + quad * 4]) = o11;
    *reinterpret_cast<fl4*>(&OL[w][32 + l16][quad * 4])      = o20;
    *reinterpret_cast<fl4*>(&OL[w][32 + l16][16 + quad * 4]) = o21;
    *reinterpret_cast<fl4*>(&OL[w][48 + l16][quad * 4])      = o30;
    *reinterpret_cast<fl4*>(&OL[w][48 + l16][16 + quad * 4]) = o31;
    if (quad == 0) {                  // ones-row sums live in D[0][q] = reg 0, quad 0
        Ll[w][ 0 + l16] = l0[0];
        Ll[w][16 + l16] = l1[0];
        Ll[w][32 + l16] = l2[0];
        Ll[w][48 + l16] = l3[0];
    }
    __syncthreads();

    // combine the 4 key-splits: thread t -> (q = t/4, 8 d-elements)
    int q = t >> 2, d0 = (t & 3) * 8;
    float rl = 1.0f / (Ll[0][q] + Ll[1][q] + Ll[2][q] + Ll[3][q]);
    fl4 a0 = *reinterpret_cast<fl4*>(&OL[0][q][d0]);
    fl4 a1 = *reinterpret_cast<fl4*>(&OL[0][q][d0 + 4]);
#pragma unroll
    for (int s = 1; s < 4; ++s) {
        fl4 b0 = *reinterpret_cast<fl4*>(&OL[s][q][d0]);
        fl4 b1 = *reinterpret_cast<fl4*>(&OL[s][q][d0 + 4]);
        a0.x += b0.x; a0.y += b0.y; a0.z += b0.z; a0.w += b0.w;
        a1.x += b1.x; a1.y += b1.y; a1.z += b1.z; a1.w += b1.w;
    }
    union { sh4 s[2]; bf16x8 v; } pk;
    pk.s[0].x = f2bf(a0.x * rl); pk.s[0].y = f2bf(a0.y * rl);
    pk.s[0].z = f2bf(a0.z * rl); pk.s[0].w = f2bf(a0.w * rl);
    pk.s[1].x = f2bf(a1.x * rl); pk.s[1].y = f2bf(a1.y * rl);
    pk.s[1].z = f2bf(a1.z * rl); pk.s[1].w = f2bf(a1.w * rl);
    int b = bh >> 3, h = bh & 7;
    *reinterpret_cast<bf16x8*>(
        Ot + ((size_t)b * N_N + q0 + q) * C_N + h * DK_N + d0) = pk.v;
}

// ---------------- kernel 4: output projection  grid(32 ct, 4 mt, 4 b) -------
__global__ __launch_bounds__(256) void oproj_kernel(
    const short* __restrict__ Wo_bf, const float* __restrict__ bo,
    const short* __restrict__ Ot, float* __restrict__ out) {
    int b = blockIdx.z, mt = blockIdx.y, ct = blockIdx.x;
    int lane = threadIdx.x & 63, w = threadIdx.x >> 6;
    int l16 = lane & 15, quad = lane >> 4;
    int m0 = mt * 64, n0 = ct * 32;
    const short* Bsrc = Ot + ((size_t)b * N_N + n0) * C_N;
    int arow = m0 + w * 16 + l16;

    f32x4 acc[2];
    acc[0] = f32x4{0.f, 0.f, 0.f, 0.f};
    acc[1] = f32x4{0.f, 0.f, 0.f, 0.f};

#pragma unroll
    for (int kc = 0; kc < 256; kc += 32) {
        bf16x8 a = *reinterpret_cast<const bf16x8*>(Wo_bf + arow * C_N + kc + quad * 8);
#pragma unroll
        for (int nt = 0; nt < 2; ++nt) {
            bf16x8 bb = *reinterpret_cast<const bf16x8*>(Bsrc + (nt * 16 + l16) * C_N + kc + quad * 8);
            acc[nt] = __builtin_amdgcn_mfma_f32_16x16x32_bf16(a, bb, acc[nt], 0, 0, 0);
        }
    }

#pragma unroll
    for (int r = 0; r < 4; ++r) {
        int row = m0 + w * 16 + quad * 4 + r;
        float bias = bo[row];
#pragma unroll
        for (int nt = 0; nt < 2; ++nt) {
            out[((size_t)b * C_N + row) * N_N + n0 + nt * 16 + l16] = acc[nt][r] + bias;
        }
    }
}

// ---------------------------------------------------------------------------
extern "C" void kernel_launch(void* const* d_in, const int* in_sizes, int n_in,
                              void* d_out, int out_size, void* d_ws, size_t ws_size,
                              hipStream_t stream) {
    const float* x0 = (const float*)d_in[0];
    const float* x1 = (const float*)d_in[1];
    const float* x2 = (const float*)d_in[2];
    const float* g0 = (const float*)d_in[3];
    const float* g1 = (const float*)d_in[4];
    const float* g2 = (const float*)d_in[5];
    const float* Wq = (const float*)d_in[6];
    const float* bq = (const float*)d_in[7];
    const float* Wk = (const float*)d_in[8];
    const float* bk = (const float*)d_in[9];
    const float* Wv = (const float*)d_in[10];
    const float* bv = (const float*)d_in[11];
    const float* Wo = (const float*)d_in[12];
    const float* bo = (const float*)d_in[13];
    float* out = (float*)d_out;

    char* wsb = (char*)d_ws;
    short* Wbf = (short*)(wsb + 0);            //  512 KB
    short* Xt  = (short*)(wsb + 524288);       // 6 MB: [12][1024][256]
    short* Qs  = (short*)(wsb + 6815744);      // 2 MB: [4][8][1024][32]
    short* Ks  = (short*)(wsb + 8912896);      // 6 MB: [4][8][3072][32]
    short* Vt  = (short*)(wsb + 15204352);     // 6 MB: [4][8][32][3072]
    short* Ot  = (short*)(wsb + 21495808);     // 2 MB: [4][1024][256]

    prep_kernel<<<dim3(16, 4, 13), 256, 0, stream>>>(x0, x1, x2, g0, g1, g2,
                                                     Wq, Wk, Wv, Wo, Xt, Wbf);
    qkv_kernel<<<dim3(112, 4, 4), 256, 0, stream>>>(Wbf, bq, bk, bv, Xt, Qs, Ks, Vt);
    attn_kernel<<<dim3(32, 16), 256, 0, stream>>>(Qs, Ks, Vt, Ot);
    oproj_kernel<<<dim3(32, 4, 4), 256, 0, stream>>>(Wbf + 3 * 65536, bo, Ot, out);
}

// Round 9
// 149.074 us; speedup vs baseline: 1.1094x; 1.1094x over previous
//
#include <hip/hip_runtime.h>

typedef short bf16x8 __attribute__((ext_vector_type(8)));
typedef float f32x4  __attribute__((ext_vector_type(4)));
typedef short sh4    __attribute__((ext_vector_type(4)));
typedef float fl4    __attribute__((ext_vector_type(4)));
typedef unsigned u32x2 __attribute__((ext_vector_type(2)));
typedef unsigned u32x4 __attribute__((ext_vector_type(4)));

#define B_N  4
#define C_N  256
#define NH_N 8
#define DK_N 32
#define N_N  1024
#define KN_N 3072

#if defined(__has_builtin)
#if __has_builtin(__builtin_amdgcn_permlane32_swap) && __has_builtin(__builtin_amdgcn_permlane16_swap)
#define USE_PERMLANE 1
#endif
#endif
#ifndef USE_PERMLANE
#define USE_PERMLANE 0
#endif

__device__ __forceinline__ short f2bf(float f) {   // RNE
    union { float f; unsigned u; } v; v.f = f;
    unsigned r = v.u + 0x7fffu + ((v.u >> 16) & 1u);
    return (short)(r >> 16);
}
__device__ __forceinline__ unsigned fbits(float f) {
    union { float f; unsigned u; } v; v.f = f; return v.u;
}

// ---------------- kernel 1: weights fp32 -> bf16 (Wq,Wk,Wv,Wo concat) -------
__global__ __launch_bounds__(256) void wcvt_kernel(
    const float* __restrict__ Wq, const float* __restrict__ Wk,
    const float* __restrict__ Wv, const float* __restrict__ Wo,
    short* __restrict__ dst) {
    int t = blockIdx.x * 256 + threadIdx.x;   // 65536 threads, 4 elems each
    int e = t * 4;
    int m = e >> 16;
    int off = e & 65535;
    const float* src = (m == 0) ? Wq : (m == 1) ? Wk : (m == 2) ? Wv : Wo;
    fl4 v = *reinterpret_cast<const fl4*>(src + off);
    sh4 o;
    o.x = f2bf(v.x); o.y = f2bf(v.y); o.z = f2bf(v.z); o.w = f2bf(v.w);
    *reinterpret_cast<sh4*>(dst + m * 65536 + off) = o;
}

// ------- kernel 2: QKV GEMM with fused stream-prep  grid(112 ct, 4 mt, 4 b) -
// Each block builds its own gamma-scaled transposed bf16 B-tile (64n x 256c)
// in LDS from the raw fp32 x streams -- the prep kernel is gone.
// ct 0-15: Q; 16-63: K; 64-111: V (operand-swapped). Epilogues repack via LDS
// so all global stores are fully-coalesced 16B chunks.
__global__ __launch_bounds__(256) void qkv_kernel(
    const short* __restrict__ Wbf, const float* __restrict__ bq,
    const float* __restrict__ bk, const float* __restrict__ bv,
    const float* __restrict__ x0, const float* __restrict__ x1,
    const float* __restrict__ x2, const float* __restrict__ g0,
    const float* __restrict__ g1, const float* __restrict__ g2,
    short* __restrict__ Qs, short* __restrict__ Ks, short* __restrict__ Vt) {
    __shared__ char smem[16640];      // fp32 stage [64][65] ALIASED with SM
    __shared__ short Bt[64][264];     // bf16 B-tile, row n, 8-short pad
    float (*stage)[65] = reinterpret_cast<float(*)[65]>(smem);
    short* SM = reinterpret_cast<short*>(smem);   // epilogue repack (Q/K 2x[64][40]; V [64][72])

    int b = blockIdx.z, mt = blockIdx.y, ct = blockIdx.x;
    int lane = threadIdx.x & 63, w = threadIdx.x >> 6;
    int l16 = lane & 15, quad = lane >> 4;
    int m0 = mt * 64;

    int type, s, n0;
    if (ct < 16)      { type = 0; s = 0;                 n0 = ct * 64; }
    else if (ct < 64) { type = 1; int c2 = ct - 16; s = c2 >> 4; n0 = (c2 & 15) * 64; }
    else              { type = 2; int c2 = ct - 64; s = c2 >> 4; n0 = (c2 & 15) * 64; }

    // ---- build B-tile: Bt[n][c] = bf16(g * x_s[b][c][n0+n]), n in [0,64) ----
    const float* xs = (s == 0) ? x0 : (s == 1) ? x1 : x2;
    float g = (s == 0) ? g0[0] : (s == 1) ? g1[0] : g2[0];
    int tx = threadIdx.x & 63, ty = threadIdx.x >> 6;
#pragma unroll
    for (int cb = 0; cb < 4; ++cb) {
        int c0 = cb * 64;
        const float* src = xs + ((size_t)(b * C_N + c0)) * N_N + n0;
#pragma unroll
        for (int r = 0; r < 16; ++r) {
            int cl = ty * 16 + r;
            stage[cl][tx] = src[cl * N_N + tx] * g;
        }
        __syncthreads();
#pragma unroll
        for (int r = 0; r < 16; ++r) {
            int nl = ty * 16 + r;
            Bt[nl][c0 + tx] = f2bf(stage[tx][nl]);
        }
        __syncthreads();
    }
    // stage is dead from here on; SM (same memory) written only after the
    // MFMA phase, which follows the barrier above -> no race.

    f32x4 acc[4];
#pragma unroll
    for (int i = 0; i < 4; ++i) acc[i] = f32x4{0.f, 0.f, 0.f, 0.f};

    if (type < 2) {
        const short* A    = Wbf + type * 65536;
        const float* bias = (type == 0) ? bq : bk;
        int arow = m0 + w * 16 + l16;
#pragma unroll
        for (int kc = 0; kc < 256; kc += 32) {
            bf16x8 a = *reinterpret_cast<const bf16x8*>(A + arow * C_N + kc + quad * 8);
#pragma unroll
            for (int nt = 0; nt < 4; ++nt) {
                bf16x8 bb = *reinterpret_cast<const bf16x8*>(&Bt[nt * 16 + l16][kc + quad * 8]);
                acc[nt] = __builtin_amdgcn_mfma_f32_16x16x32_bf16(a, bb, acc[nt], 0, 0, 0);
            }
        }
        const float QSCALE = 0.17677669529663687f * 1.4426950408889634f;
        int row0 = m0 + w * 16 + quad * 4;
        float b0_ = bias[row0], b1_ = bias[row0 + 1], b2_ = bias[row0 + 2], b3_ = bias[row0 + 3];
        int dk0 = (w & 1) * 16 + quad * 4;
        short* Tp = SM + (w >> 1) * 2560 + dk0;    // + pos*40
#pragma unroll
        for (int nt = 0; nt < 4; ++nt) {
            int pos = nt * 16 + l16;
            float v0 = acc[nt][0] + b0_, v1 = acc[nt][1] + b1_;
            float v2 = acc[nt][2] + b2_, v3 = acc[nt][3] + b3_;
            sh4 pk;
            if (type == 0) {
                pk.x = f2bf(v0 * QSCALE); pk.y = f2bf(v1 * QSCALE);
                pk.z = f2bf(v2 * QSCALE); pk.w = f2bf(v3 * QSCALE);
            } else {
                pk.x = f2bf(v0); pk.y = f2bf(v1); pk.z = f2bf(v2); pk.w = f2bf(v3);
            }
            *reinterpret_cast<sh4*>(Tp + pos * 40) = pk;
        }
        __syncthreads();
        int t = threadIdx.x;
        int pos_l = t >> 2, seg = t & 3;
#pragma unroll
        for (int hl = 0; hl < 2; ++hl) {
            bf16x8 vv = *reinterpret_cast<const bf16x8*>(SM + hl * 2560 + pos_l * 40 + seg * 8);
            int h = 2 * mt + hl;
            if (type == 0) {
                size_t base = ((size_t)(b * NH_N + h) * N_N + n0) * DK_N;
                *reinterpret_cast<bf16x8*>(Qs + base + t * 8) = vv;
            } else {
                size_t base = ((size_t)(b * NH_N + h) * KN_N + s * N_N + n0) * DK_N;
                *reinterpret_cast<bf16x8*>(Ks + base + t * 8) = vv;
            }
        }
    } else {
        const short* Bw = Wbf + 2 * 65536;
#pragma unroll
        for (int kc = 0; kc < 256; kc += 32) {
            bf16x8 ax = *reinterpret_cast<const bf16x8*>(&Bt[w * 16 + l16][kc + quad * 8]);
#pragma unroll
            for (int c2 = 0; c2 < 4; ++c2) {
                bf16x8 bw = *reinterpret_cast<const bf16x8*>(Bw + (size_t)(m0 + c2 * 16 + l16) * C_N + kc + quad * 8);
                acc[c2] = __builtin_amdgcn_mfma_f32_16x16x32_bf16(ax, bw, acc[c2], 0, 0, 0);
            }
        }
        int key0 = w * 16 + quad * 4;
#pragma unroll
        for (int c2 = 0; c2 < 4; ++c2) {
            int row = c2 * 16 + l16;
            float bb_ = bv[m0 + row];
            sh4 pk;
            pk.x = f2bf(acc[c2][0] + bb_); pk.y = f2bf(acc[c2][1] + bb_);
            pk.z = f2bf(acc[c2][2] + bb_); pk.w = f2bf(acc[c2][3] + bb_);
            *reinterpret_cast<sh4*>(SM + row * 72 + key0) = pk;
        }
        __syncthreads();
        int t = threadIdx.x;
#pragma unroll
        for (int i = 0; i < 2; ++i) {
            int ch = t + i * 256;
            int row = ch >> 3, seg = ch & 7;
            bf16x8 vv = *reinterpret_cast<const bf16x8*>(SM + row * 72 + seg * 8);
            int co = m0 + row;
            int h = co >> 5, d = co & 31;
            *reinterpret_cast<bf16x8*>(
                Vt + ((size_t)(b * NH_N + h) * DK_N + d) * KN_N + s * N_N + n0 + seg * 8) = vv;
        }
    }
}

// -------- kernel 3: fused attention, 4 waves = 4 key-splits (r5 exact) ------
// Each wave holds FOUR q-fragments (64 q rows) and loads each K/V fragment
// ONCE -> 4x less VMEM traffic than one-q-frag-per-wave.
struct Frags { bf16x8 k0, k1, k2, k3, v00, v01, v10, v11; };

__device__ __forceinline__ Frags ldfr(const short* Kp, const short* Vp0, int k0) {
    Frags f;
    f.k0  = *reinterpret_cast<const bf16x8*>(Kp + (k0 +  0) * DK_N);
    f.k1  = *reinterpret_cast<const bf16x8*>(Kp + (k0 + 16) * DK_N);
    f.k2  = *reinterpret_cast<const bf16x8*>(Kp + (k0 + 32) * DK_N);
    f.k3  = *reinterpret_cast<const bf16x8*>(Kp + (k0 + 48) * DK_N);
    f.v00 = *reinterpret_cast<const bf16x8*>(Vp0 + k0);
    f.v01 = *reinterpret_cast<const bf16x8*>(Vp0 + 16 * KN_N + k0);
    f.v10 = *reinterpret_cast<const bf16x8*>(Vp0 + k0 + 32);
    f.v11 = *reinterpret_cast<const bf16x8*>(Vp0 + 16 * KN_N + k0 + 32);
    return f;
}

#define EXPPACK(sv, Ra, Rb, LACC) {                             \
    float p0 = __builtin_amdgcn_exp2f(sv[0]);                   \
    float p1 = __builtin_amdgcn_exp2f(sv[1]);                   \
    float p2 = __builtin_amdgcn_exp2f(sv[2]);                   \
    float p3 = __builtin_amdgcn_exp2f(sv[3]);                   \
    LACC += (p0 + p1) + (p2 + p3);                              \
    Ra = __builtin_amdgcn_perm(fbits(p1), fbits(p0), 0x07060302u); \
    Rb = __builtin_amdgcn_perm(fbits(p3), fbits(p2), 0x07060302u); \
}

#if USE_PERMLANE
// In-register C-layout -> B-layout transpose via gfx950 permlane swaps.
#define PVSTEP(RA0, RA1, RB0, RB1, VF0, VF1, O0, O1) {                 \
    unsigned x0 = RA0, y0 = RB0, x1 = RA1, y1 = RB1;                   \
    u32x2 r_;                                                          \
    r_ = __builtin_amdgcn_permlane32_swap(x0, y0, false, false); x0 = r_.x; y0 = r_.y; \
    r_ = __builtin_amdgcn_permlane16_swap(x0, y0, false, false); x0 = r_.x; y0 = r_.y; \
    r_ = __builtin_amdgcn_permlane32_swap(x1, y1, false, false); x1 = r_.x; y1 = r_.y; \
    r_ = __builtin_amdgcn_permlane16_swap(x1, y1, false, false); x1 = r_.x; y1 = r_.y; \
    union { u32x4 u; bf16x8 b; } pf_; pf_.u = u32x4{x0, x1, y0, y1};   \
    O0 = __builtin_amdgcn_mfma_f32_16x16x32_bf16(VF0, pf_.b, O0, 0, 0, 0); \
    O1 = __builtin_amdgcn_mfma_f32_16x16x32_bf16(VF1, pf_.b, O1, 0, 0, 0); \
}
#else
// Fallback (also satisfies the host compile pass): per-wave-private LDS
// round-trip, no barrier needed.
#define PVSTEP(RA0, RA1, RB0, RB1, VF0, VF1, O0, O1) {                 \
    union { u32x2 u; sh4 s; } wa_, wb_;                                \
    wa_.u = u32x2{RA0, RA1}; wb_.u = u32x2{RB0, RB1};                  \
    *reinterpret_cast<sh4*>(&PT[w][l16][quad * 4])      = wa_.s;       \
    *reinterpret_cast<sh4*>(&PT[w][l16][16 + quad * 4]) = wb_.s;       \
    bf16x8 pf_ = *reinterpret_cast<bf16x8*>(&PT[w][l16][quad * 8]);    \
    O0 = __builtin_amdgcn_mfma_f32_16x16x32_bf16(VF0, pf_, O0, 0, 0, 0); \
    O1 = __builtin_amdgcn_mfma_f32_16x16x32_bf16(VF1, pf_, O1, 0, 0, 0); \
}
#endif

// One 64-key tile x one 16-row q-fragment
#define PROCJ(f, QF, LACC, O0, O1) {                                     \
    f32x4 s0 = __builtin_amdgcn_mfma_f32_16x16x32_bf16(f.k0, QF, zero, 0, 0, 0); \
    f32x4 s1 = __builtin_amdgcn_mfma_f32_16x16x32_bf16(f.k1, QF, zero, 0, 0, 0); \
    f32x4 s2 = __builtin_amdgcn_mfma_f32_16x16x32_bf16(f.k2, QF, zero, 0, 0, 0); \
    f32x4 s3 = __builtin_amdgcn_mfma_f32_16x16x32_bf16(f.k3, QF, zero, 0, 0, 0); \
    unsigned R00, R01, R10, R11, R20, R21, R30, R31;                     \
    EXPPACK(s0, R00, R01, LACC); EXPPACK(s1, R10, R11, LACC);            \
    EXPPACK(s2, R20, R21, LACC); EXPPACK(s3, R30, R31, LACC);            \
    PVSTEP(R00, R01, R10, R11, f.v00, f.v01, O0, O1);                    \
    PVSTEP(R20, R21, R30, R31, f.v10, f.v11, O0, O1);                    \
}

#define PROCALL(f) {                                                     \
    PROCJ(f, qf0, la0, o00, o01);                                        \
    PROCJ(f, qf1, la1, o10, o11);                                        \
    PROCJ(f, qf2, la2, o20, o21);                                        \
    PROCJ(f, qf3, la3, o30, o31);                                        \
}

__global__ __launch_bounds__(256, 2) void attn_kernel(
    const short* __restrict__ Qs, const short* __restrict__ Ks,
    const short* __restrict__ Vt, short* __restrict__ Ot) {
    __shared__ float OL[4][64][36];   // [split][q][d] partial O, 36 KB
    __shared__ float Ll[4][64];       // [split][q] partial rowsum
#if !USE_PERMLANE
    __shared__ short PT[4][16][36];
#endif

    int bh = blockIdx.x;
    int q0 = blockIdx.y * 64;
    int t = threadIdx.x, lane = t & 63, w = t >> 6;   // w = key-split 0..3
    int l16 = lane & 15, quad = lane >> 4;

    const short* Qbase = Qs + ((size_t)bh * N_N + q0 + l16) * DK_N + quad * 8;
    bf16x8 qf0 = *reinterpret_cast<const bf16x8*>(Qbase + 0 * 16 * DK_N);
    bf16x8 qf1 = *reinterpret_cast<const bf16x8*>(Qbase + 1 * 16 * DK_N);
    bf16x8 qf2 = *reinterpret_cast<const bf16x8*>(Qbase + 2 * 16 * DK_N);
    bf16x8 qf3 = *reinterpret_cast<const bf16x8*>(Qbase + 3 * 16 * DK_N);
    const short* Kp  = Ks + ((size_t)bh * KN_N + l16) * DK_N + quad * 8;
    const short* Vp0 = Vt + ((size_t)bh * DK_N + l16) * KN_N + quad * 8;

    const f32x4 zero = {0.f, 0.f, 0.f, 0.f};
    f32x4 o00 = zero, o01 = zero, o10 = zero, o11 = zero;
    f32x4 o20 = zero, o21 = zero, o30 = zero, o31 = zero;
    float la0 = 0.f, la1 = 0.f, la2 = 0.f, la3 = 0.f;
    int kbase = w * 768;              // this wave's 768-key slice, 12 tiles

    Frags cur = ldfr(Kp, Vp0, kbase);
#pragma unroll 2
    for (int i = 0; i < 11; ++i) {
        Frags nxt = ldfr(Kp, Vp0, kbase + (i + 1) * 64);   // prefetch next tile
        PROCALL(cur);
        cur = nxt;
    }
    PROCALL(cur);

    // reduce each la over the 4 quads (all lanes end with the total)
    la0 += __shfl_xor(la0, 16); la0 += __shfl_xor(la0, 32);
    la1 += __shfl_xor(la1, 16); la1 += __shfl_xor(la1, 32);
    la2 += __shfl_xor(la2, 16); la2 += __shfl_xor(la2, 32);
    la3 += __shfl_xor(la3, 16); la3 += __shfl_xor(la3, 32);

    *reinterpret_cast<fl4*>(&OL[w][ 0 + l16][quad * 4])      = o00;
    *reinterpret_cast<fl4*>(&OL[w][ 0 + l16][16 + quad * 4]) = o01;
    *reinterpret_cast<fl4*>(&OL[w][16 + l16][quad * 4])      = o10;
    *reinterpret_cast<fl4*>(&OL[w][16 + l16][16 + quad * 4]) = o11;
    *reinterpret_cast<fl4*>(&OL[w][32 + l16][quad * 4])      = o20;
    *reinterpret_cast<fl4*>(&OL[w][32 + l16][16 + quad * 4]) = o21;
    *reinterpret_cast<fl4*>(&OL[w][48 + l16][quad * 4])      = o30;
    *reinterpret_cast<fl4*>(&OL[w][48 + l16][16 + quad * 4]) = o31;
    if (quad == 0) {
        Ll[w][ 0 + l16] = la0;
        Ll[w][16 + l16] = la1;
        Ll[w][32 + l16] = la2;
        Ll[w][48 + l16] = la3;
    }
    __syncthreads();

    // combine the 4 key-splits: thread t -> (q = t/4, 8 d-elements)
    int q = t >> 2, d0 = (t & 3) * 8;
    float rl = 1.0f / (Ll[0][q] + Ll[1][q] + Ll[2][q] + Ll[3][q]);
    fl4 a0 = *reinterpret_cast<fl4*>(&OL[0][q][d0]);
    fl4 a1 = *reinterpret_cast<fl4*>(&OL[0][q][d0 + 4]);
#pragma unroll
    for (int s = 1; s < 4; ++s) {
        fl4 b0 = *reinterpret_cast<fl4*>(&OL[s][q][d0]);
        fl4 b1 = *reinterpret_cast<fl4*>(&OL[s][q][d0 + 4]);
        a0.x += b0.x; a0.y += b0.y; a0.z += b0.z; a0.w += b0.w;
        a1.x += b1.x; a1.y += b1.y; a1.z += b1.z; a1.w += b1.w;
    }
    union { sh4 s[2]; bf16x8 v; } pk;
    pk.s[0].x = f2bf(a0.x * rl); pk.s[0].y = f2bf(a0.y * rl);
    pk.s[0].z = f2bf(a0.z * rl); pk.s[0].w = f2bf(a0.w * rl);
    pk.s[1].x = f2bf(a1.x * rl); pk.s[1].y = f2bf(a1.y * rl);
    pk.s[1].z = f2bf(a1.z * rl); pk.s[1].w = f2bf(a1.w * rl);
    int b = bh >> 3, h = bh & 7;
    *reinterpret_cast<bf16x8*>(
        Ot + ((size_t)b * N_N + q0 + q) * C_N + h * DK_N + d0) = pk.v;
}

// ---------------- kernel 4: output projection  grid(32 ct, 4 mt, 4 b) -------
__global__ __launch_bounds__(256) void oproj_kernel(
    const short* __restrict__ Wo_bf, const float* __restrict__ bo,
    const short* __restrict__ Ot, float* __restrict__ out) {
    int b = blockIdx.z, mt = blockIdx.y, ct = blockIdx.x;
    int lane = threadIdx.x & 63, w = threadIdx.x >> 6;
    int l16 = lane & 15, quad = lane >> 4;
    int m0 = mt * 64, n0 = ct * 32;
    const short* Bsrc = Ot + ((size_t)b * N_N + n0) * C_N;
    int arow = m0 + w * 16 + l16;

    f32x4 acc[2];
    acc[0] = f32x4{0.f, 0.f, 0.f, 0.f};
    acc[1] = f32x4{0.f, 0.f, 0.f, 0.f};

#pragma unroll
    for (int kc = 0; kc < 256; kc += 32) {
        bf16x8 a = *reinterpret_cast<const bf16x8*>(Wo_bf + arow * C_N + kc + quad * 8);
#pragma unroll
        for (int nt = 0; nt < 2; ++nt) {
            bf16x8 bb = *reinterpret_cast<const bf16x8*>(Bsrc + (nt * 16 + l16) * C_N + kc + quad * 8);
            acc[nt] = __builtin_amdgcn_mfma_f32_16x16x32_bf16(a, bb, acc[nt], 0, 0, 0);
        }
    }

#pragma unroll
    for (int r = 0; r < 4; ++r) {
        int row = m0 + w * 16 + quad * 4 + r;
        float bias = bo[row];
#pragma unroll
        for (int nt = 0; nt < 2; ++nt) {
            out[((size_t)b * C_N + row) * N_N + n0 + nt * 16 + l16] = acc[nt][r] + bias;
        }
    }
}

// ---------------------------------------------------------------------------
extern "C" void kernel_launch(void* const* d_in, const int* in_sizes, int n_in,
                              void* d_out, int out_size, void* d_ws, size_t ws_size,
                              hipStream_t stream) {
    const float* x0 = (const float*)d_in[0];
    const float* x1 = (const float*)d_in[1];
    const float* x2 = (const float*)d_in[2];
    const float* g0 = (const float*)d_in[3];
    const float* g1 = (const float*)d_in[4];
    const float* g2 = (const float*)d_in[5];
    const float* Wq = (const float*)d_in[6];
    const float* bq = (const float*)d_in[7];
    const float* Wk = (const float*)d_in[8];
    const float* bk = (const float*)d_in[9];
    const float* Wv = (const float*)d_in[10];
    const float* bv = (const float*)d_in[11];
    const float* Wo = (const float*)d_in[12];
    const float* bo = (const float*)d_in[13];
    float* out = (float*)d_out;

    char* wsb = (char*)d_ws;
    short* Wbf = (short*)(wsb + 0);            //  512 KB
    short* Qs  = (short*)(wsb + 6815744);      // 2 MB: [4][8][1024][32]
    short* Ks  = (short*)(wsb + 8912896);      // 6 MB: [4][8][3072][32]
    short* Vt  = (short*)(wsb + 15204352);     // 6 MB: [4][8][32][3072]
    short* Ot  = (short*)(wsb + 21495808);     // 2 MB: [4][1024][256]

    wcvt_kernel<<<256, 256, 0, stream>>>(Wq, Wk, Wv, Wo, Wbf);
    qkv_kernel<<<dim3(112, 4, 4), 256, 0, stream>>>(Wbf, bq, bk, bv,
                                                    x0, x1, x2, g0, g1, g2,
                                                    Qs, Ks, Vt);
    attn_kernel<<<dim3(32, 16), 256, 0, stream>>>(Qs, Ks, Vt, Ot);
    oproj_kernel<<<dim3(32, 4, 4), 256, 0, stream>>>(Wbf + 3 * 65536, bo, Ot, out);
}